// Round 1
// baseline (2993.881 us; speedup 1.0000x reference)
//
#include <hip/hip_runtime.h>
#include <math.h>

#define NN 4
#define C 128          // inC == outC
#define DD 16
#define HH 64
#define WW 64
#define LL 512
#define EPSF 1e-8f

// ---------------- style[n,c] = latent[n,:] . fc_w[c,:] + fc_b[c] ----------------
__global__ __launch_bounds__(64) void k_style(const float* __restrict__ latent,
                                              const float* __restrict__ fc_w,
                                              const float* __restrict__ fc_b,
                                              float* __restrict__ style) {
    int b = blockIdx.x;          // 0..511  (n*128 + c)
    int n = b >> 7, c = b & 127;
    int lane = threadIdx.x;
    const float* lat = latent + n * LL;
    const float* w   = fc_w   + c * LL;
    float s = 0.f;
    for (int l = lane; l < LL; l += 64) s += lat[l] * w[l];
    #pragma unroll
    for (int off = 32; off; off >>= 1) s += __shfl_down(s, off);
    if (lane == 0) style[b] = s + fc_b[c];
}

// ---------------- s2[oc,ic] = sum_t weight[oc,ic,t]^2 ----------------
__global__ __launch_bounds__(128) void k_s2(const float* __restrict__ weight,
                                            float* __restrict__ s2) {
    int oc = blockIdx.x, ic = threadIdx.x;
    const float* src = weight + (oc * C + ic) * 27;
    float s = 0.f;
    #pragma unroll
    for (int t = 0; t < 27; ++t) { float v = src[t]; s += v * v; }
    s2[oc * C + ic] = s;
}

// ---------------- Wt[kdh][ic][kw][oc] = weight[oc][ic][kd][kh][kw] ----------------
__global__ __launch_bounds__(128) void k_wt(const float* __restrict__ weight,
                                            float* __restrict__ Wt) {
    int b = blockIdx.x;            // 0..1151 (kdh*128 + ic)
    int kdh = b >> 7, ic = b & 127;
    int oc = threadIdx.x;
    const float* src = weight + (oc * C + ic) * 27 + kdh * 3;
    float w0 = src[0], w1 = src[1], w2 = src[2];
    float* dst = Wt + ((kdh * C + ic) * 3) * C + oc;
    dst[0]     = w0;
    dst[C]     = w1;
    dst[2 * C] = w2;
}

// ---------------- demod[n,oc] = rsqrt(sum_ic s2[oc,ic]*style[n,ic]^2 + eps) -------
__global__ __launch_bounds__(64) void k_demod(const float* __restrict__ s2,
                                              const float* __restrict__ style,
                                              float* __restrict__ demod) {
    int b = blockIdx.x;            // 0..511 (n*128 + oc)
    int n = b >> 7, oc = b & 127;
    int lane = threadIdx.x;
    float s = 0.f;
    for (int ic = lane; ic < C; ic += 64) {
        float st = style[n * C + ic];
        s += s2[oc * C + ic] * st * st;
    }
    #pragma unroll
    for (int off = 32; off; off >>= 1) s += __shfl_down(s, off);
    if (lane == 0) demod[b] = rsqrtf(s + EPSF);
}

// ---------------- main conv ----------------
// Block: one (n, d, h-pair). Tile: 128 oc x (2 h x 64 w). 256 threads,
// each computes 8 oc x 8 w. K-loop: (kd,kh) outer x ic inner = 1152 steps.
// x is scaled by style[n,ic] at staging; output scaled by demod[n,oc] at store.
__global__ __launch_bounds__(256, 2) void k_conv(const float* __restrict__ x,
                                                 const float* __restrict__ Wt,
                                                 const float* __restrict__ style,
                                                 const float* __restrict__ demod,
                                                 float* __restrict__ out) {
    __shared__ float xs[2][68];    // [row][j], j=0..65 maps to w' = j-1 (halo)
    __shared__ float wl[3][C];     // [kw][oc]
    __shared__ float st[C];

    const int hb = blockIdx.x;     // 0..31
    const int d  = blockIdx.y;     // 0..15
    const int n  = blockIdx.z;     // 0..3
    const int h0 = hb * 2;
    const int tid = threadIdx.x;
    const int ocg = tid >> 4;      // 0..15
    const int wg  = tid & 15;
    const int oc0 = ocg * 8;
    const int r   = wg >> 3;       // 0..1  (which h row)
    const int w0  = (wg & 7) * 8;  // 0,8,...,56

    if (tid < C) st[tid] = style[n * C + tid];

    float acc[8][8];
    #pragma unroll
    for (int o = 0; o < 8; ++o)
        #pragma unroll
        for (int q = 0; q < 8; ++q) acc[o][q] = 0.f;

    const int t = tid - 96;        // staging role for x rows

    for (int kdh = 0; kdh < 9; ++kdh) {
        const int kd = kdh / 3, kh = kdh - 3 * kd;
        const int zd  = d + kd - 1;
        const int zh0 = h0 + kh - 1;
        for (int ic = 0; ic < C; ++ic) {
            __syncthreads();   // protect LDS from previous step's readers
            if (tid < 96) {
                // 96 threads x float4 = 384 floats = Wt slice [3][128]
                const float4* src = (const float4*)(Wt + (kdh * C + ic) * 3 * C);
                ((float4*)wl)[tid] = src[tid];
            } else if (t < 132) {
                const int rr = (t < 66) ? 0 : 1;
                const int j  = (t < 66) ? t : t - 66;
                const int wq = j - 1;
                const int zh = zh0 + rr;
                float v = 0.f;
                if (zd >= 0 && zd < DD && zh >= 0 && zh < HH && (unsigned)wq < WW)
                    v = x[((((size_t)n * C + ic) * DD + zd) * HH + zh) * WW + wq] * st[ic];
                xs[rr][j] = v;
            }
            __syncthreads();

            float xv[10];
            #pragma unroll
            for (int j = 0; j < 10; ++j) xv[j] = xs[r][w0 + j];
            #pragma unroll
            for (int kw = 0; kw < 3; ++kw) {
                #pragma unroll
                for (int o = 0; o < 8; ++o) {
                    const float wv = wl[kw][oc0 + o];
                    #pragma unroll
                    for (int q = 0; q < 8; ++q)
                        acc[o][q] = fmaf(wv, xv[q + kw], acc[o][q]);
                }
            }
        }
    }

    const int h = h0 + r;
    #pragma unroll
    for (int o = 0; o < 8; ++o) {
        const float dm = demod[n * C + oc0 + o];
        float* dst = out + ((((size_t)n * C + oc0 + o) * DD + d) * HH + h) * WW + w0;
        float4 v0 = make_float4(acc[o][0] * dm, acc[o][1] * dm,
                                acc[o][2] * dm, acc[o][3] * dm);
        float4 v1 = make_float4(acc[o][4] * dm, acc[o][5] * dm,
                                acc[o][6] * dm, acc[o][7] * dm);
        ((float4*)dst)[0] = v0;
        ((float4*)dst)[1] = v1;
    }
}

extern "C" void kernel_launch(void* const* d_in, const int* in_sizes, int n_in,
                              void* d_out, int out_size, void* d_ws, size_t ws_size,
                              hipStream_t stream) {
    const float* x      = (const float*)d_in[0];
    const float* latent = (const float*)d_in[1];
    const float* weight = (const float*)d_in[2];
    const float* fc_w   = (const float*)d_in[3];
    const float* fc_b   = (const float*)d_in[4];
    float* out = (float*)d_out;
    float* ws  = (float*)d_ws;

    float* style = ws;                    // 512 floats
    float* demod = ws + 512;              // 512 floats
    float* s2    = ws + 1024;             // 16384 floats
    float* Wt    = ws + 1024 + 16384;     // 442368 floats (~1.77 MB)
    // total ws use ≈ 1.84 MB

    hipLaunchKernelGGL(k_style, dim3(NN * C), dim3(64), 0, stream,
                       latent, fc_w, fc_b, style);
    hipLaunchKernelGGL(k_s2,    dim3(C), dim3(C), 0, stream, weight, s2);
    hipLaunchKernelGGL(k_wt,    dim3(9 * C), dim3(C), 0, stream, weight, Wt);
    hipLaunchKernelGGL(k_demod, dim3(NN * C), dim3(64), 0, stream,
                       s2, style, demod);
    hipLaunchKernelGGL(k_conv,  dim3(32, DD, NN), dim3(256), 0, stream,
                       x, Wt, style, demod, out);
}

// Round 2
// 771.840 us; speedup vs baseline: 3.8789x; 3.8789x over previous
//
#include <hip/hip_runtime.h>
#include <math.h>

#define NN 4
#define C 128          // inC == outC
#define DD 16
#define HH 64
#define WW 64
#define LL 512
#define EPSF 1e-8f

typedef __attribute__((ext_vector_type(8)))  short short8;
typedef __attribute__((ext_vector_type(16))) float f32x16;

__device__ __forceinline__ unsigned short f2bf(float f) {
    unsigned u = __float_as_uint(f);
    unsigned r = (u + 0x7fffu + ((u >> 16) & 1u)) >> 16;
    return (unsigned short)r;
}
__device__ __forceinline__ float bf2f(unsigned short h) {
    return __uint_as_float(((unsigned)h) << 16);
}

// ---------------- style[n,c] = latent[n,:] . fc_w[c,:] + fc_b[c] ----------------
__global__ __launch_bounds__(64) void k_style(const float* __restrict__ latent,
                                              const float* __restrict__ fc_w,
                                              const float* __restrict__ fc_b,
                                              float* __restrict__ style) {
    int b = blockIdx.x;          // n*128 + c
    int n = b >> 7, c = b & 127;
    int lane = threadIdx.x;
    const float* lat = latent + n * LL;
    const float* w   = fc_w   + c * LL;
    float s = 0.f;
    for (int l = lane; l < LL; l += 64) s += lat[l] * w[l];
    #pragma unroll
    for (int off = 32; off; off >>= 1) s += __shfl_down(s, off);
    if (lane == 0) style[b] = s + fc_b[c];
}

// ---------------- s2[oc,ic] = sum_t weight[oc,ic,t]^2 ----------------
__global__ __launch_bounds__(128) void k_s2(const float* __restrict__ weight,
                                            float* __restrict__ s2) {
    int oc = blockIdx.x, ic = threadIdx.x;
    const float* src = weight + (oc * C + ic) * 27;
    float s = 0.f;
    #pragma unroll
    for (int t = 0; t < 27; ++t) { float v = src[t]; s += v * v; }
    s2[oc * C + ic] = s;
}

// ---------------- demod[n,oc] = rsqrt(sum_ic s2[oc,ic]*style[n,ic]^2 + eps) ------
__global__ __launch_bounds__(64) void k_demod(const float* __restrict__ s2,
                                              const float* __restrict__ style,
                                              float* __restrict__ demod) {
    int b = blockIdx.x;            // n*128 + oc
    int n = b >> 7, oc = b & 127;
    int lane = threadIdx.x;
    float s = 0.f;
    for (int ic = lane; ic < C; ic += 64) {
        float st = style[n * C + ic];
        s += s2[oc * C + ic] * st * st;
    }
    #pragma unroll
    for (int off = 32; off; off >>= 1) s += __shfl_down(s, off);
    if (lane == 0) demod[b] = rsqrtf(s + EPSF);
}

// ------- Wt[kdh 9][cc 8][part 2][kw 3][oc 128][i 16] (ushort bf16) -------
// part 0 = hi = bf16(w); part 1 = lo = bf16(w - hi)
__global__ __launch_bounds__(256) void k_wt(const float* __restrict__ w,
                                            unsigned short* __restrict__ Wt) {
    int b = blockIdx.x;            // 0..71 : kdh*8 + cc
    int kdh = b >> 3, cc = b & 7;
    int kd = kdh / 3, kh = kdh - 3 * kd;
    for (int e = threadIdx.x; e < 12288; e += 256) {
        int i  = e & 15;
        int oc = (e >> 4) & 127;
        int t  = e >> 11;          // part*3 + kw
        int part = t / 3, kw = t - 3 * part;
        int ic = cc * 16 + i;
        float v = w[(oc * C + ic) * 27 + kd * 9 + kh * 3 + kw];
        unsigned short hv = f2bf(v);
        unsigned short ov = (part == 0) ? hv : f2bf(v - bf2f(hv));
        Wt[(size_t)b * 12288 + e] = ov;
    }
}

// ---------------- main conv: implicit GEMM with bf16-split MFMA ----------------
// Block: (n, d, 2 h-rows) x 128 oc x 64 w. 4 waves, each 64oc x (1 row x 64 w)
// as 2x2 tiles of mfma_f32_32x32x16_bf16. 72 stages (9 kdh x 8 ic-chunks of 16).
__global__ __launch_bounds__(256, 2) void k_conv(
        const float* __restrict__ x,
        const unsigned short* __restrict__ Wt,
        const float* __restrict__ style,
        const float* __restrict__ demod,
        float* __restrict__ out) {

    __shared__ __align__(16) unsigned short wld[2][3][C][16];     // 24576 B
    __shared__ __align__(16) unsigned short xld[2][2][2][66][8];  // 16896 B
    __shared__ float stl[C], dml[C];

    const int hb = blockIdx.x;     // 0..31
    const int d  = blockIdx.y;     // 0..15
    const int n  = blockIdx.z;     // 0..3
    const int h0 = hb * 2;
    const int tid  = threadIdx.x;
    const int lane = tid & 63;
    const int wv   = tid >> 6;     // wave 0..3
    const int wr   = wv >> 1;      // oc half
    const int wc   = wv & 1;       // h row

    if (tid < C)            stl[tid]      = style[n * C + tid];
    else if (tid < 2 * C)   dml[tid - C]  = demod[n * C + tid - C];
    if (tid < 16) {                // zero w-halo slots (image-border pad), once
        int part = tid >> 3, row = (tid >> 2) & 1, icb = (tid >> 1) & 1, e = tid & 1;
        short8 z = (short8)0;
        *(short8*)&xld[part][row][icb][e ? 65 : 0][0] = z;
    }

    // staging thread mapping: (row, icb, w)
    const int srow = tid >> 7;
    const int sicb = (tid >> 6) & 1;
    const int sw   = tid & 63;

    f32x16 acc[2][2] = {};

    const int l31  = lane & 31;
    const int kreg = lane >> 5;

    for (int kdh = 0; kdh < 9; ++kdh) {
        const int kd = kdh / 3, kh = kdh - 3 * kd;
        const int zd = d + kd - 1;
        const int zh = h0 + kh - 1 + srow;
        const bool valid = ((unsigned)zd < DD) && ((unsigned)zh < HH);
        const float* xrow = x + ((((size_t)n * C) * DD + zd) * HH + zh) * WW + sw;

        for (int cc = 0; cc < 8; ++cc) {
            __syncthreads();   // protect LDS from previous stage's readers

            // ---- stage weights: 24 KB via global_load_lds, 6 chunks/wave ----
            {
                const unsigned short* gW = Wt + (size_t)(kdh * 8 + cc) * 12288;
                unsigned short* wflat = &wld[0][0][0][0];
                #pragma unroll
                for (int c2 = 0; c2 < 6; ++c2) {
                    const int chunk = wv * 6 + c2;
                    const unsigned short* src = gW + chunk * 512 + lane * 8;
                    unsigned short* dst = wflat + chunk * 512;
                    __builtin_amdgcn_global_load_lds(
                        (const __attribute__((address_space(1))) unsigned int*)src,
                        (__attribute__((address_space(3))) unsigned int*)dst,
                        16, 0, 0);
                }
            }

            // ---- stage x: scale by style, split hi/lo, blocked transpose ----
            if (valid) {
                const float* xs = xrow + ((size_t)(cc * 16 + sicb * 8)) * (DD * HH * WW);
                const float* stp = &stl[cc * 16 + sicb * 8];
                short8 vh, vl;
                #pragma unroll
                for (int j = 0; j < 8; ++j) {
                    float v = xs[(size_t)j * (DD * HH * WW)] * stp[j];
                    unsigned short h = f2bf(v);
                    vh[j] = (short)h;
                    vl[j] = (short)f2bf(v - bf2f(h));
                }
                *(short8*)&xld[0][srow][sicb][1 + sw][0] = vh;
                *(short8*)&xld[1][srow][sicb][1 + sw][0] = vl;
            } else {
                short8 z = (short8)0;
                *(short8*)&xld[0][srow][sicb][1 + sw][0] = z;
                *(short8*)&xld[1][srow][sicb][1 + sw][0] = z;
            }
            __syncthreads();

            // ---- compute: 3 kw x (2 oc-tiles x 2 sp-tiles) x 3-term split ----
            #pragma unroll
            for (int kw = 0; kw < 3; ++kw) {
                short8 a[2][2], b[2][2];
                #pragma unroll
                for (int o = 0; o < 2; ++o) {
                    const int oc = wr * 64 + o * 32 + l31;
                    a[o][0] = *(const short8*)&wld[0][kw][oc][kreg * 8];
                    a[o][1] = *(const short8*)&wld[1][kw][oc][kreg * 8];
                }
                #pragma unroll
                for (int p = 0; p < 2; ++p) {
                    const int wpos = p * 32 + l31 + kw;   // (w_out + kw - 1) + 1
                    b[p][0] = *(const short8*)&xld[0][wc][kreg][wpos][0];
                    b[p][1] = *(const short8*)&xld[1][wc][kreg][wpos][0];
                }
                #pragma unroll
                for (int o = 0; o < 2; ++o)
                    #pragma unroll
                    for (int p = 0; p < 2; ++p) {
                        acc[o][p] = __builtin_amdgcn_mfma_f32_32x32x16_bf16(
                                        a[o][0], b[p][0], acc[o][p], 0, 0, 0);
                        acc[o][p] = __builtin_amdgcn_mfma_f32_32x32x16_bf16(
                                        a[o][0], b[p][1], acc[o][p], 0, 0, 0);
                        acc[o][p] = __builtin_amdgcn_mfma_f32_32x32x16_bf16(
                                        a[o][1], b[p][0], acc[o][p], 0, 0, 0);
                    }
            }
        }
    }

    // ---- epilogue: demod scale + store ----
    const int lhi = lane >> 5;
    const int h = h0 + wc;
    #pragma unroll
    for (int o = 0; o < 2; ++o) {
        #pragma unroll
        for (int r = 0; r < 16; ++r) {
            const int ocrow = (r & 3) + 8 * (r >> 2) + 4 * lhi;
            const int oc = wr * 64 + o * 32 + ocrow;
            const float dm = dml[oc];
            #pragma unroll
            for (int p = 0; p < 2; ++p) {
                const int wq = p * 32 + l31;
                out[((((size_t)n * C + oc) * DD + d) * HH + h) * WW + wq] =
                    acc[o][p][r] * dm;
            }
        }
    }
}

extern "C" void kernel_launch(void* const* d_in, const int* in_sizes, int n_in,
                              void* d_out, int out_size, void* d_ws, size_t ws_size,
                              hipStream_t stream) {
    const float* x      = (const float*)d_in[0];
    const float* latent = (const float*)d_in[1];
    const float* weight = (const float*)d_in[2];
    const float* fc_w   = (const float*)d_in[3];
    const float* fc_b   = (const float*)d_in[4];
    float* out = (float*)d_out;

    float* style = (float*)d_ws;                    // 512 f32
    float* demod = style + 512;                     // 512 f32
    float* s2    = demod + 512;                     // 16384 f32
    unsigned short* Wt = (unsigned short*)(s2 + 16384);  // 884736 ushort (~1.77 MB)

    hipLaunchKernelGGL(k_style, dim3(NN * C), dim3(64), 0, stream,
                       latent, fc_w, fc_b, style);
    hipLaunchKernelGGL(k_s2,    dim3(C), dim3(C), 0, stream, weight, s2);
    hipLaunchKernelGGL(k_wt,    dim3(72), dim3(256), 0, stream, weight, Wt);
    hipLaunchKernelGGL(k_demod, dim3(NN * C), dim3(64), 0, stream,
                       s2, style, demod);
    hipLaunchKernelGGL(k_conv,  dim3(32, DD, NN), dim3(256), 0, stream,
                       x, Wt, style, demod, out);
}